// Round 5
// baseline (388.262 us; speedup 1.0000x reference)
//
#include <hip/hip_runtime.h>
#include <hip/hip_bf16.h>

#define N_NODES 100000
#define N_EDGES 1600000

#define NBKT 782                 // ceil(N_NODES / 128)
#define SCAT_BLOCKS 240
#define BKT_CHUNK 6667           // ceil(N_EDGES / 240)

#define SORT_BLOCKS 40
#define SORT_CHUNK 2500          // 40 * 2500 = 100000
#define BH2_N (NBKT * SCAT_BLOCKS)   // 187680
#define BHB ((BH2_N + 1023) / 1024)  // 184
#define XBF_BLOCKS 6250              // N_NODES*16/256

#define FG_BLOCKS 782            // ceil(N_NODES / 128 rows-per-block)

typedef __attribute__((ext_vector_type(8))) short short8v;
typedef __attribute__((ext_vector_type(4))) float float4v;

__device__ __forceinline__ unsigned short f2bf(float f) {
    unsigned int u = __float_as_uint(f);
    u = (u + 0x7FFFu + ((u >> 16) & 1u)) >> 16;   // RTNE
    return (unsigned short)u;
}
__device__ __forceinline__ float bf2f(unsigned short b) {
    return __uint_as_float((unsigned int)b << 16);
}

// async global->LDS, 16B per lane. LDS dest must be linear (wave base + lane*16);
// swizzle goes on the GLOBAL source address (rule #21: both-sides-or-neither).
typedef __attribute__((address_space(1))) const unsigned int gld_g_t;
typedef __attribute__((address_space(3))) unsigned int gld_l_t;
__device__ __forceinline__ void gld_lds16(const void* g, void* l) {
    __builtin_amdgcn_global_load_lds((gld_g_t*)g, (gld_l_t*)l, 16, 0, 0);
}

// swizzled ds_read index (shorts): XOR byte ^= ((row&7)<<4) within a row
#define SWZ128(row, ksh) ((row) * 128 + ((ksh) ^ (((row) & 7) << 3)))   // 128-short rows
#define SWZ256(row, ksh) ((row) * 256 + ((ksh) ^ (((row) & 7) << 3)))   // 256-short rows

// accumulate a short8v (bf16x8) into two float4v
#define GACC(u, A, B) { A[0] += bf2f((unsigned short)u[0]); A[1] += bf2f((unsigned short)u[1]); \
                        A[2] += bf2f((unsigned short)u[2]); A[3] += bf2f((unsigned short)u[3]); \
                        B[0] += bf2f((unsigned short)u[4]); B[1] += bf2f((unsigned short)u[5]); \
                        B[2] += bf2f((unsigned short)u[6]); B[3] += bf2f((unsigned short)u[7]); }

__device__ __forceinline__ short8v pack_bf(const float4v lo, const float4v hi, float di) {
    short8v r;
    r[0] = f2bf(lo[0] * di); r[1] = f2bf(lo[1] * di); r[2] = f2bf(lo[2] * di); r[3] = f2bf(lo[3] * di);
    r[4] = f2bf(hi[0] * di); r[5] = f2bf(hi[1] * di); r[6] = f2bf(hi[2] * di); r[7] = f2bf(hi[3] * di);
    return r;
}

// ---------------- merged: bucket histogram (blocks 0..239) + x->bf16 (blocks 240..) ----------------
__global__ __launch_bounds__(256) void hist_xbf_kernel(const int* __restrict__ ei, int* __restrict__ bh2,
                                                       const float* __restrict__ x, unsigned short* __restrict__ xsrc) {
    __shared__ int h[NBKT];
    int tid = threadIdx.x;
    if (blockIdx.x < SCAT_BLOCKS) {
        for (int i = tid; i < NBKT; i += 256) h[i] = 0;
        __syncthreads();
        int start = blockIdx.x * BKT_CHUNK;
        int end = start + BKT_CHUNK; if (end > N_EDGES) end = N_EDGES;
        for (int i = start + tid; i < end; i += 256) {
            int d = ei[N_EDGES + i];
            atomicAdd(&h[d >> 7], 1);
        }
        __syncthreads();
        for (int i = tid; i < NBKT; i += 256) bh2[i * SCAT_BLOCKS + blockIdx.x] = h[i];
    } else {
        int idx = (blockIdx.x - SCAT_BLOCKS) * 256 + tid;   // one float4 per thread
        if (idx < N_NODES * 16) {
            int node = idx >> 4;
            int f0 = (idx & 15) * 4;
            float4 v = *(const float4*)(x + (size_t)idx * 4);
            ushort4 o;
            o.x = f2bf(v.x); o.y = f2bf(v.y); o.z = f2bf(v.z); o.w = f2bf(v.w);
            *(ushort4*)(xsrc + (size_t)node * 64 + f0) = o;
        }
    }
}

__global__ __launch_bounds__(256) void gscan_a_kernel(const int* __restrict__ in, int* __restrict__ bsum, int n) {
    __shared__ int lds[256];
    int tid = threadIdx.x;
    int base = blockIdx.x * 1024 + tid * 4;
    int s = 0;
    #pragma unroll
    for (int i = 0; i < 4; i++) s += (base + i < n) ? in[base + i] : 0;
    lds[tid] = s;
    __syncthreads();
    for (int off = 128; off; off >>= 1) {
        if (tid < off) lds[tid] += lds[tid + off];
        __syncthreads();
    }
    if (tid == 0) bsum[blockIdx.x] = lds[0];
}

// in-place exclusive scan apply; each block self-scans bsum (<=256 entries) in LDS
__global__ __launch_bounds__(256) void gscan_c_kernel(int* __restrict__ data, const int* __restrict__ bsum,
                                                      int nb, int n) {
    __shared__ int sb[256];
    __shared__ int lds[256];
    int tid = threadIdx.x;
    sb[tid] = (tid < nb) ? bsum[tid] : 0;
    __syncthreads();
    for (int off = 1; off < 256; off <<= 1) {
        int y = 0;
        if (tid >= off) y = sb[tid - off];
        __syncthreads();
        if (tid >= off) sb[tid] += y;
        __syncthreads();
    }
    int blockbase = (blockIdx.x == 0) ? 0 : sb[blockIdx.x - 1];

    int base = blockIdx.x * 1024 + tid * 4;
    int v[4];
    int s = 0;
    #pragma unroll
    for (int i = 0; i < 4; i++) {
        v[i] = (base + i < n) ? data[base + i] : 0;
        s += v[i];
    }
    lds[tid] = s;
    __syncthreads();
    for (int off = 1; off < 256; off <<= 1) {
        int y = 0;
        if (tid >= off) y = lds[tid - off];
        __syncthreads();
        if (tid >= off) lds[tid] += y;
        __syncthreads();
    }
    int run = blockbase + lds[tid] - s;
    #pragma unroll
    for (int i = 0; i < 4; i++) {
        if (base + i < n) data[base + i] = run;
        run += v[i];
    }
}

__global__ __launch_bounds__(256) void bkt_scatter2_kernel(const int* __restrict__ ei, const int* __restrict__ bh2,
                                                           int* __restrict__ packed) {
    __shared__ int h[NBKT];
    __shared__ int base[NBKT];
    int tid = threadIdx.x;
    for (int i = tid; i < NBKT; i += 256) { h[i] = 0; base[i] = bh2[i * SCAT_BLOCKS + blockIdx.x]; }
    __syncthreads();
    int start = blockIdx.x * BKT_CHUNK;
    int end = start + BKT_CHUNK; if (end > N_EDGES) end = N_EDGES;
    for (int i = start + tid; i < end; i += 256) {
        int s = ei[i];
        int d = ei[N_EDGES + i];
        int b = d >> 7;
        int pos = base[b] + atomicAdd(&h[b], 1);
        packed[pos] = (s << 7) | (d & 127);
    }
}

// merged: per-bucket degree count + LDS scan -> deg[], row_ptr[]; then fill col.
__global__ __launch_bounds__(256) void bkt_build_kernel(const int* __restrict__ packed, const int* __restrict__ bh2,
                                                        int* __restrict__ deg, int* __restrict__ row_ptr,
                                                        int* __restrict__ col) {
    __shared__ int c[128];
    __shared__ int rp[128];
    int tid = threadIdx.x;
    int s0 = bh2[blockIdx.x * SCAT_BLOCKS];
    int s1 = (blockIdx.x + 1 < NBKT) ? bh2[(blockIdx.x + 1) * SCAT_BLOCKS] : N_EDGES;
    if (tid < 128) c[tid] = 0;
    __syncthreads();
    for (int i = s0 + tid; i < s1; i += 256) atomicAdd(&c[packed[i] & 127], 1);
    __syncthreads();
    if (tid < 128) rp[tid] = c[tid];
    __syncthreads();
    for (int off = 1; off < 128; off <<= 1) {
        int y = 0;
        if (tid >= off && tid < 128) y = rp[tid - off];
        __syncthreads();
        if (tid >= off && tid < 128) rp[tid] += y;
        __syncthreads();
    }
    int node = blockIdx.x * 128 + tid;
    if (tid < 128) {
        rp[tid] = s0 + rp[tid] - c[tid];   // exclusive in-bucket prefix + bucket base
        if (node < N_NODES) {
            deg[node] = c[tid];
            row_ptr[node] = rp[tid];
        }
        c[tid] = 0;
    }
    if (blockIdx.x == 0 && tid == 0) row_ptr[N_NODES] = N_EDGES;
    __syncthreads();
    for (int i = s0 + tid; i < s1; i += 256) {
        int p = packed[i];
        int dl = p & 127;
        int pos = rp[dl] + atomicAdd(&c[dl], 1);
        col[pos] = p >> 7;
    }
}

// ---------------- degree counting sort (DESCENDING) -> ord[] ----------------
// Descending so long blocks launch first AND ord-adjacent nodes have equal degrees
// (the fused GEMM assigns 16 consecutive ord-slots to one wave -> uniform lane loops).
__global__ __launch_bounds__(256) void dsort_hist_kernel(const int* __restrict__ deg, int* __restrict__ bh) {
    __shared__ int h[64];
    int tid = threadIdx.x;
    if (tid < 64) h[tid] = 0;
    __syncthreads();
    int start = blockIdx.x * SORT_CHUNK;
    int end = start + SORT_CHUNK; if (end > N_NODES) end = N_NODES;
    for (int i = start + tid; i < end; i += 256) atomicAdd(&h[63 - min(deg[i], 63)], 1);
    __syncthreads();
    if (tid < 64) bh[tid * SORT_BLOCKS + blockIdx.x] = h[tid];
}

// scatter; each block self-scans the full bh[2560] in LDS (exclusive prefix)
__global__ __launch_bounds__(256) void dsort_scat_kernel(const int* __restrict__ deg, const int* __restrict__ bh,
                                                         int* __restrict__ ord) {
    __shared__ int sbh[64 * SORT_BLOCKS];
    __shared__ int ps[256];
    __shared__ int h[64];
    int tid = threadIdx.x;
    int v[10];
    int s = 0;
    #pragma unroll
    for (int k = 0; k < 10; k++) { v[k] = bh[tid * 10 + k]; s += v[k]; }
    ps[tid] = s;
    if (tid < 64) h[tid] = 0;
    __syncthreads();
    for (int off = 1; off < 256; off <<= 1) {
        int y = 0;
        if (tid >= off) y = ps[tid - off];
        __syncthreads();
        if (tid >= off) ps[tid] += y;
        __syncthreads();
    }
    int run = ps[tid] - s;
    #pragma unroll
    for (int k = 0; k < 10; k++) { sbh[tid * 10 + k] = run; run += v[k]; }
    __syncthreads();
    int start = blockIdx.x * SORT_CHUNK;
    int end = start + SORT_CHUNK; if (end > N_NODES) end = N_NODES;
    for (int i = start + tid; i < end; i += 256) {
        int b = 63 - min(deg[i], 63);
        int pos = sbh[b * SORT_BLOCKS + blockIdx.x] + atomicAdd(&h[b], 1);
        ord[pos] = i;
    }
}

// ---------------- all weight preps in one launch (bf16 transposed) ----------------
__global__ __launch_bounds__(256) void wprep_all_kernel(const float* __restrict__ Wr1, const float* __restrict__ Wl1,
                                                        const float* __restrict__ Wres,
                                                        const float* __restrict__ Wl2, const float* __restrict__ Wr2,
                                                        const float* __restrict__ Wl3, const float* __restrict__ Wr3,
                                                        unsigned short* __restrict__ Bt1,
                                                        unsigned short* __restrict__ Bt2,
                                                        unsigned short* __restrict__ Bt3) {
    int idx = blockIdx.x * 256 + threadIdx.x;
    int seg = idx >> 15;          // 32768 elements per segment
    int loc = idx & 32767;
    if (seg == 0) {
        int n = loc >> 7;
        int k = loc & 127;
        float v;
        if (n < 128) v = (k < 64) ? Wr1[k * 128 + n] : Wl1[(k - 64) * 128 + n];
        else         v = (k < 64) ? Wres[k * 128 + (n - 128)] : 0.f;
        Bt1[loc] = f2bf(v);
    } else if (seg == 1) {
        int n = loc >> 8;
        int k = loc & 255;
        float v = (k < 128) ? Wr2[k * 128 + n] : Wl2[(k - 128) * 128 + n];
        Bt2[loc] = f2bf(v);
    } else if (seg == 2) {
        int n = loc >> 8;
        int k = loc & 255;
        float v = (k < 128) ? Wr3[k * 128 + n] : Wl3[(k - 128) * 128 + n];
        Bt3[loc] = f2bf(v);
    }
}

// ---------------- layer-1 FUSED gather+GEMM+LN ----------------
// Each lane owns one ord-mapped row: gathers its neighbor-mean slices into registers
// (replacing agg64 + aggx roundtrip), then streams into MFMA. One barrier total.
__global__ __launch_bounds__(512) void fgemm1_ln_kernel(const unsigned short* __restrict__ xsrc,
                                                        const unsigned short* __restrict__ Bt,
                                                        const int* __restrict__ row_ptr, const int* __restrict__ col,
                                                        const int* __restrict__ ord,
                                                        const float* __restrict__ b1, const float* __restrict__ ln_g,
                                                        const float* __restrict__ ln_b, const float* __restrict__ bres,
                                                        unsigned short* __restrict__ hsrc) {
    __shared__ unsigned short Bs[32768];   // 256 n-rows x 128 k (rows 0..127 = [Wr1|Wl1], 128..255 = Wres)
    int tid = threadIdx.x;
    int wave = tid >> 6, lane = tid & 63;
    int lm = lane & 15, lk = (lane >> 4) * 8;

    #pragma unroll
    for (int rnd = 0; rnd < 8; rnd++) {           // async B stage; latency hidden under gather
        int Lb = rnd * 8192 + tid * 16;
        int row = Lb >> 8;
        int sb = (Lb & 255) ^ ((row & 7) << 4);
        gld_lds16(Bt + (size_t)row * 128 + (sb >> 1), &Bs[Lb >> 1]);
    }

    int slot = blockIdx.x * 128 + wave * 16 + lm;
    if (slot >= N_NODES) slot = N_NODES - 1;      // dup rows write identical bytes (benign)
    int i = ord[slot];
    int rs = row_ptr[i], re = row_ptr[i + 1];

    // direct A fragments (row i, x part) — issue early
    short8v ad0 = *(const short8v*)(xsrc + (size_t)i * 64 + lk);
    short8v ad1 = *(const short8v*)(xsrc + (size_t)i * 64 + 32 + lk);

    // gather: mean over neighbors of row i, slices [lk..lk+8) and [32+lk..+8)
    float4v a0 = (float4v)0.f, a1 = (float4v)0.f, a2 = (float4v)0.f, a3 = (float4v)0.f;
    const unsigned short* xb = xsrc + lk;
    int t = rs;
    for (; t + 3 < re; t += 4) {
        int j0 = col[t], j1 = col[t + 1], j2 = col[t + 2], j3 = col[t + 3];
        short8v u0 = *(const short8v*)(xb + (size_t)j0 * 64);
        short8v v0 = *(const short8v*)(xb + (size_t)j0 * 64 + 32);
        short8v u1 = *(const short8v*)(xb + (size_t)j1 * 64);
        short8v v1 = *(const short8v*)(xb + (size_t)j1 * 64 + 32);
        short8v u2 = *(const short8v*)(xb + (size_t)j2 * 64);
        short8v v2 = *(const short8v*)(xb + (size_t)j2 * 64 + 32);
        short8v u3 = *(const short8v*)(xb + (size_t)j3 * 64);
        short8v v3 = *(const short8v*)(xb + (size_t)j3 * 64 + 32);
        GACC(u0, a0, a1) GACC(v0, a2, a3)
        GACC(u1, a0, a1) GACC(v1, a2, a3)
        GACC(u2, a0, a1) GACC(v2, a2, a3)
        GACC(u3, a0, a1) GACC(v3, a2, a3)
    }
    for (; t < re; t++) {
        int j0 = col[t];
        short8v u0 = *(const short8v*)(xb + (size_t)j0 * 64);
        short8v v0 = *(const short8v*)(xb + (size_t)j0 * 64 + 32);
        GACC(u0, a0, a1) GACC(v0, a2, a3)
    }
    float di = 1.0f / fmaxf((float)(re - rs), 1.0f);
    short8v ag0 = pack_bf(a0, a1, di);
    short8v ag1 = pack_bf(a2, a3, di);

    __syncthreads();   // B staged; all lanes done

    float4v accT[8], accR[8];
    #pragma unroll
    for (int j = 0; j < 8; j++) { accT[j] = (float4v)0.f; accR[j] = (float4v)0.f; }

    #pragma unroll
    for (int k0 = 0; k0 < 128; k0 += 32) {
        short8v af = (k0 == 0) ? ad0 : (k0 == 32) ? ad1 : (k0 == 64) ? ag0 : ag1;
        #pragma unroll
        for (int j = 0; j < 8; j++) {
            short8v bfv = *(const short8v*)&Bs[SWZ128(j * 16 + lm, k0 + lk)];
            accT[j] = __builtin_amdgcn_mfma_f32_16x16x32_bf16(af, bfv, accT[j], 0, 0, 0);
        }
        if (k0 < 64) {                            // residual path only has k<64 support
            #pragma unroll
            for (int j = 0; j < 8; j++) {
                short8v bg = *(const short8v*)&Bs[SWZ128(128 + j * 16 + lm, k0 + lk)];
                accR[j] = __builtin_amdgcn_mfma_f32_16x16x32_bf16(af, bg, accR[j], 0, 0, 0);
            }
        }
    }

    float b1v[8], gv[8], bbv[8], brv[8];
    #pragma unroll
    for (int j = 0; j < 8; j++) {
        int cc = j * 16 + lm;
        b1v[j] = b1[cc]; gv[j] = ln_g[cc]; bbv[j] = ln_b[cc]; brv[j] = bres[cc];
    }
    int q4 = lane >> 4;
    #pragma unroll
    for (int r = 0; r < 4; r++) {
        float sp = 0.f, sq = 0.f;
        #pragma unroll
        for (int j = 0; j < 8; j++) {
            float tv = accT[j][r] + b1v[j];
            sp += tv; sq += tv * tv;
        }
        #pragma unroll
        for (int off = 1; off < 16; off <<= 1) {
            sp += __shfl_xor(sp, off);
            sq += __shfl_xor(sq, off);
        }
        float mu = sp * (1.f / 128.f);
        float var = sq * (1.f / 128.f) - mu * mu;
        float rstd = rsqrtf(var + 1e-5f);
        int gm = __shfl(i, q4 * 4 + r, 16);       // row held by lane lm == q4*4+r (any 16-group)
        #pragma unroll
        for (int j = 0; j < 8; j++) {
            float tv = accT[j][r] + b1v[j];
            float y = fmaxf((tv - mu) * rstd * gv[j] + bbv[j], 0.f) + accR[j][r] + brv[j];
            hsrc[(size_t)gm * 128 + j * 16 + lm] = f2bf(y);
        }
    }
}

// ---------------- layers 2/3 FUSED gather+GEMM (256-k) ----------------
// PQ=0: writes relu(out+bias) bf16 to C. PQ=1: fused p/q epilogue (h3 never stored).
template <int PQ>
__global__ __launch_bounds__(512) void fgemm128_kernel(const unsigned short* __restrict__ H,
                                                       const unsigned short* __restrict__ Bt,
                                                       const int* __restrict__ row_ptr, const int* __restrict__ col,
                                                       const int* __restrict__ ord,
                                                       const float* __restrict__ bias,
                                                       unsigned short* __restrict__ C,
                                                       const float* __restrict__ Wl4, const float* __restrict__ Wr4,
                                                       const float* __restrict__ b4,
                                                       float* __restrict__ p, float* __restrict__ q) {
    __shared__ unsigned short Bs[32768];   // 128 n-rows x 256 k
    int tid = threadIdx.x;
    int wave = tid >> 6, lane = tid & 63;
    int lm = lane & 15, lk = (lane >> 4) * 8;

    #pragma unroll
    for (int rnd = 0; rnd < 8; rnd++) {           // async B stage
        int Lb = rnd * 8192 + tid * 16;
        int row = Lb >> 9;                        // 512B rows
        int sb = (Lb & 511) ^ ((row & 7) << 4);
        gld_lds16(Bt + ((size_t)row << 8) + (sb >> 1), &Bs[Lb >> 1]);
    }

    int slot = blockIdx.x * 128 + wave * 16 + lm;
    if (slot >= N_NODES) slot = N_NODES - 1;
    int i = ord[slot];
    int rs = row_ptr[i], re = row_ptr[i + 1];

    // direct A fragments (row i of H)
    short8v ad0 = *(const short8v*)(H + (size_t)i * 128 + lk);
    short8v ad1 = *(const short8v*)(H + (size_t)i * 128 + 32 + lk);
    short8v ad2 = *(const short8v*)(H + (size_t)i * 128 + 64 + lk);
    short8v ad3 = *(const short8v*)(H + (size_t)i * 128 + 96 + lk);

    // gather: mean over neighbors, 4 slices of 8 shorts at {0,32,64,96}+lk
    float4v a0 = (float4v)0.f, a1 = (float4v)0.f, a2 = (float4v)0.f, a3 = (float4v)0.f;
    float4v a4 = (float4v)0.f, a5 = (float4v)0.f, a6 = (float4v)0.f, a7 = (float4v)0.f;
    const unsigned short* hb = H + lk;
    int t = rs;
    for (; t + 1 < re; t += 2) {
        int j0 = col[t], j1 = col[t + 1];
        short8v u0 = *(const short8v*)(hb + (size_t)j0 * 128);
        short8v u1 = *(const short8v*)(hb + (size_t)j0 * 128 + 32);
        short8v u2 = *(const short8v*)(hb + (size_t)j0 * 128 + 64);
        short8v u3 = *(const short8v*)(hb + (size_t)j0 * 128 + 96);
        short8v w0 = *(const short8v*)(hb + (size_t)j1 * 128);
        short8v w1 = *(const short8v*)(hb + (size_t)j1 * 128 + 32);
        short8v w2 = *(const short8v*)(hb + (size_t)j1 * 128 + 64);
        short8v w3 = *(const short8v*)(hb + (size_t)j1 * 128 + 96);
        GACC(u0, a0, a1) GACC(u1, a2, a3) GACC(u2, a4, a5) GACC(u3, a6, a7)
        GACC(w0, a0, a1) GACC(w1, a2, a3) GACC(w2, a4, a5) GACC(w3, a6, a7)
    }
    if (t < re) {
        int j0 = col[t];
        short8v u0 = *(const short8v*)(hb + (size_t)j0 * 128);
        short8v u1 = *(const short8v*)(hb + (size_t)j0 * 128 + 32);
        short8v u2 = *(const short8v*)(hb + (size_t)j0 * 128 + 64);
        short8v u3 = *(const short8v*)(hb + (size_t)j0 * 128 + 96);
        GACC(u0, a0, a1) GACC(u1, a2, a3) GACC(u2, a4, a5) GACC(u3, a6, a7)
    }
    float di = 1.0f / fmaxf((float)(re - rs), 1.0f);
    short8v ag0 = pack_bf(a0, a1, di);
    short8v ag1 = pack_bf(a2, a3, di);
    short8v ag2 = pack_bf(a4, a5, di);
    short8v ag3 = pack_bf(a6, a7, di);

    __syncthreads();   // B staged

    float4v acc[8];
    #pragma unroll
    for (int j = 0; j < 8; j++) acc[j] = (float4v)0.f;

    #pragma unroll
    for (int k0 = 0; k0 < 256; k0 += 32) {
        short8v af = (k0 == 0) ? ad0 : (k0 == 32) ? ad1 : (k0 == 64) ? ad2 : (k0 == 96) ? ad3
                   : (k0 == 128) ? ag0 : (k0 == 160) ? ag1 : (k0 == 192) ? ag2 : ag3;
        #pragma unroll
        for (int j = 0; j < 8; j++) {
            short8v bfv = *(const short8v*)&Bs[SWZ256(j * 16 + lm, k0 + lk)];
            acc[j] = __builtin_amdgcn_mfma_f32_16x16x32_bf16(af, bfv, acc[j], 0, 0, 0);
        }
    }

    int q4 = lane >> 4;
    int gmv[4];
    #pragma unroll
    for (int r = 0; r < 4; r++) gmv[r] = __shfl(i, q4 * 4 + r, 16);

    if (PQ == 0) {
        #pragma unroll
        for (int j = 0; j < 8; j++) {
            int cc = j * 16 + lm;
            float bv = bias[cc];
            #pragma unroll
            for (int r = 0; r < 4; r++)
                C[(size_t)gmv[r] * 128 + cc] = f2bf(fmaxf(acc[j][r] + bv, 0.f));
        }
    } else {
        float b3v[8], wlv[8], wrv[8];
        #pragma unroll
        for (int j = 0; j < 8; j++) {
            int cc = j * 16 + lm;
            b3v[j] = bias[cc]; wlv[j] = Wl4[cc]; wrv[j] = Wr4[cc];
        }
        float b4v = b4[0];
        #pragma unroll
        for (int r = 0; r < 4; r++) {
            float pp = 0.f, qq = 0.f;
            #pragma unroll
            for (int j = 0; j < 8; j++) {
                float hv = fmaxf(acc[j][r] + b3v[j], 0.f);
                pp += hv * wlv[j]; qq += hv * wrv[j];
            }
            #pragma unroll
            for (int off = 1; off < 16; off <<= 1) {
                pp += __shfl_xor(pp, off);
                qq += __shfl_xor(qq, off);
            }
            if (lm == 0) {
                p[gmv[r]] = pp;
                q[gmv[r]] = qq + b4v;
            }
        }
    }
}

__global__ __launch_bounds__(256) void final_kernel(const float* __restrict__ p, const float* __restrict__ q,
                                                    const int* __restrict__ row_ptr, const int* __restrict__ col,
                                                    float* __restrict__ out) {
    int i = blockIdx.x * 256 + threadIdx.x;   // original node id
    if (i >= N_NODES) return;
    int s = row_ptr[i], e = row_ptr[i + 1];
    float acc = 0.f;
    int t = s;
    for (; t + 7 < e; t += 8)
        acc += p[col[t]] + p[col[t + 1]] + p[col[t + 2]] + p[col[t + 3]]
             + p[col[t + 4]] + p[col[t + 5]] + p[col[t + 6]] + p[col[t + 7]];
    for (; t < e; t++) acc += p[col[t]];
    float di = 1.0f / fmaxf((float)(e - s), 1.0f);
    out[i] = acc * di + q[i];
}

// ---------------- launch ----------------

extern "C" void kernel_launch(void* const* d_in, const int* in_sizes, int n_in,
                              void* d_out, int out_size, void* d_ws, size_t ws_size,
                              hipStream_t stream) {
    const float* x    = (const float*)d_in[0];
    const int*   ei   = (const int*)d_in[1];
    const float* Wl1  = (const float*)d_in[2];
    const float* Wr1  = (const float*)d_in[3];
    const float* b1   = (const float*)d_in[4];
    const float* ln_g = (const float*)d_in[5];
    const float* ln_b = (const float*)d_in[6];
    const float* Wres = (const float*)d_in[7];
    const float* bres = (const float*)d_in[8];
    const float* Wl2  = (const float*)d_in[9];
    const float* Wr2  = (const float*)d_in[10];
    const float* b2   = (const float*)d_in[11];
    const float* Wl3  = (const float*)d_in[12];
    const float* Wr3  = (const float*)d_in[13];
    const float* b3   = (const float*)d_in[14];
    const float* Wl4  = (const float*)d_in[15];
    const float* Wr4  = (const float*)d_in[16];
    const float* b4   = (const float*)d_in[17];
    float* out = (float*)d_out;

    char* w = (char*)d_ws;
    size_t off = 0;
    auto alloc = [&](size_t bytes) -> void* {
        off = (off + 255) & ~(size_t)255;
        void* pp = w + off;
        off += bytes;
        return pp;
    };

    int*   deg        = (int*)alloc(N_NODES * 4);
    int*   row_ptr    = (int*)alloc((N_NODES + 1) * 4);
    int*   bsum       = (int*)alloc(1024);
    int*   col        = (int*)alloc(N_EDGES * 4);
    int*   bh2        = (int*)alloc(BH2_N * 4);
    int*   bh         = (int*)alloc(64 * SORT_BLOCKS * 4);
    int*   ord        = (int*)alloc(N_NODES * 4);       // sorted slot -> original node (desc degree)
    unsigned short* Bt1  = (unsigned short*)alloc(256 * 128 * 2);
    unsigned short* Bt2  = (unsigned short*)alloc(128 * 256 * 2);
    unsigned short* Bt3  = (unsigned short*)alloc(128 * 256 * 2);
    unsigned short* xsrc = (unsigned short*)alloc((size_t)N_NODES * 64 * 2);   // x bf16 (compact)
    unsigned short* hsrc = (unsigned short*)alloc((size_t)N_NODES * 128 * 2);  // h1
    unsigned short* h2   = (unsigned short*)alloc((size_t)N_NODES * 128 * 2);  // h2 (no in-place: fused gather reads hsrc)
    int*   packed  = (int*)alloc((size_t)N_EDGES * 4);   // CSR build scratch
    float* p       = (float*)alloc(N_NODES * 4);
    float* q       = (float*)alloc(N_NODES * 4);
    (void)ws_size; (void)n_in; (void)in_sizes; (void)out_size;

    const int NB = (N_NODES + 255) / 256;

    // --- weight prep (independent, front-loaded) ---
    wprep_all_kernel<<<384, 256, 0, stream>>>(Wr1, Wl1, Wres, Wl2, Wr2, Wl3, Wr3, Bt1, Bt2, Bt3);

    // --- CSR build (original space) + x conversion overlapped ---
    hist_xbf_kernel<<<SCAT_BLOCKS + XBF_BLOCKS, 256, 0, stream>>>(ei, bh2, x, xsrc);
    gscan_a_kernel<<<BHB, 256, 0, stream>>>(bh2, bsum, BH2_N);
    gscan_c_kernel<<<BHB, 256, 0, stream>>>(bh2, bsum, BHB, BH2_N);
    bkt_scatter2_kernel<<<SCAT_BLOCKS, 256, 0, stream>>>(ei, bh2, packed);
    bkt_build_kernel<<<NBKT, 256, 0, stream>>>(packed, bh2, deg, row_ptr, col);
    dsort_hist_kernel<<<SORT_BLOCKS, 256, 0, stream>>>(deg, bh);
    dsort_scat_kernel<<<SORT_BLOCKS, 256, 0, stream>>>(deg, bh, ord);

    // --- layer 1: fused gather(x)+GEMM+LN -> hsrc ---
    fgemm1_ln_kernel<<<FG_BLOCKS, 512, 0, stream>>>(xsrc, Bt1, row_ptr, col, ord,
                                                    b1, ln_g, ln_b, bres, hsrc);

    // --- layer 2: fused gather(h1)+GEMM -> h2 (bias+relu) ---
    fgemm128_kernel<0><<<FG_BLOCKS, 512, 0, stream>>>(hsrc, Bt2, row_ptr, col, ord,
                                                      b2, h2, nullptr, nullptr, nullptr, nullptr, nullptr);

    // --- layer 3: fused gather(h2)+GEMM+pq -> p, q (h3 never stored) ---
    fgemm128_kernel<1><<<FG_BLOCKS, 512, 0, stream>>>(h2, Bt3, row_ptr, col, ord,
                                                      b3, nullptr, Wl4, Wr4, b4, p, q);

    // --- final ---
    final_kernel<<<NB, 256, 0, stream>>>(p, q, row_ptr, col, out);
}